// Round 1
// 489.931 us; speedup vs baseline: 1.1152x; 1.1152x over previous
//
#include <hip/hip_runtime.h>
#include <hip/hip_fp16.h>

// Fused neural-CA step on MI355X (gfx950).
//   z  = leaky(depthwise_conv5x5_D4sym(psi) + b1)
//   h  = leaky(w2 z + b2);  out = tanh(psi + w3 h + b3)
//
// Round 2 changes (vs 545us baseline):
//  - SLAB 16 -> 8 (SROWS 12), grid 2048*8. LDS 39.9KB -> 22.1KB
//    => 7 blocks/CU (28 waves/CU, 87.5% occ) instead of 4 (50%).
//    Theory: kernel was latency-bound (VALUBusy 57%, HBM 22%, occ 44%);
//    more resident blocks hide barrier drains + LDS/global latency.
//  - __launch_bounds__(256, 8) pins VGPR<=64 (was 52) so VGPRs never cap
//    occupancy below the LDS limit.
//  - Packed fp32 math: conv horizontal combine and both 8x8 GEMMs written
//    as float2 ext-vectors so the backend emits v_pk_fma_f32/v_pk_add_f32
//    (full-rate on CDNA4) -> ~halves the dominant VALU streams.
//  - Everything else (fp16 LDS staging, 2-way-bank-free strides, D4 6-weight
//    decomposition, fast tanh) unchanged.

#define HIDDEN 8
#define RES    64
#define SLAB   8
#define SROWS  12   // SLAB + 4 halo rows
#define SSTR2  35   // psi tile row stride in __half2 units (70 halves)
#define ZSTR2  33   // z tile row stride in __half2 units (66 halves)

typedef float v2f __attribute__((ext_vector_type(2)));

#define PV(a, i) ((v2f){ (a)[(i)], (a)[(i) + 1] })

__global__ __launch_bounds__(256, 8)
void ca_fused(const float* __restrict__ psi,
              const float* __restrict__ filter1,
              const float* __restrict__ bias1,
              const float* __restrict__ w2,
              const float* __restrict__ b2,
              const float* __restrict__ w3,
              const float* __restrict__ b3,
              float* __restrict__ out)
{
    __shared__ __half2 s_in[HIDDEN * SROWS * SSTR2];  // 3360 pairs = 13440 B
    __shared__ __half2 s_z [HIDDEN * SLAB  * ZSTR2];  // 2112 pairs =  8448 B
    __shared__ float   s_coef[HIDDEN * 8];            // A,B,C,D,E,F,bias1,pad

    const int tid  = threadIdx.x;
    const int b    = blockIdx.x >> 3;
    const int slab = blockIdx.x & 7;
    const int y0   = slab * SLAB;

    const float* psib = psi + (size_t)b * (HIDDEN * RES * RES);

    // ---- totalistic coefficients, one thread per channel ----
    if (tid < HIDDEN) {
        const float* f = filter1 + tid * 25;
        float x[25];
        float m = 0.f;
        #pragma unroll
        for (int i = 0; i < 25; ++i) { x[i] = f[i]; m += x[i]; }
        m *= 0.04f;  // /25
        // orbits of D4 on the 5x5 grid (flat index i*5+j)
        float A = x[12] - m;                                          // center
        float B = 0.25f  * (x[7]+x[17]+x[11]+x[13]) - m;              // edge-1
        float C = 0.25f  * (x[6]+x[8]+x[16]+x[18]) - m;               // diag-1
        float D = 0.25f  * (x[2]+x[22]+x[10]+x[14]) - m;              // edge-2
        float E = 0.125f * (x[1]+x[3]+x[21]+x[23]+x[5]+x[15]+x[9]+x[19]) - m; // knight
        float F = 0.25f  * (x[0]+x[4]+x[20]+x[24]) - m;               // corner
        s_coef[tid*8+0] = A; s_coef[tid*8+1] = B; s_coef[tid*8+2] = C;
        s_coef[tid*8+3] = D; s_coef[tid*8+4] = E; s_coef[tid*8+5] = F;
        s_coef[tid*8+6] = bias1[tid];
    }

    // ---- stage psi slab into LDS as fp16 pairs (zero halo) ----
    // pairs px in [0,34): px 0 and 33 are the zero pad, 1..32 map to gx 0..63
    for (int p = tid; p < HIDDEN * SROWS * 34; p += 256) {
        int c   = p / (SROWS * 34);
        int rem = p - c * (SROWS * 34);
        int r   = rem / 34;
        int px  = rem - r * 34;
        int gy  = y0 - 2 + r;
        float2 v = make_float2(0.f, 0.f);
        if ((unsigned)gy < RES && px >= 1 && px <= 32)
            v = *(const float2*)(psib + ((c << 12) | (gy << 6)) + (2*px - 2));
        s_in[(c * SROWS + r) * SSTR2 + px] = __floats2half2_rn(v.x, v.y);
    }
    __syncthreads();

    // ---- phase 1: depthwise conv + bias + leaky -> s_z ----
    // job = (c, y, seg): 16 output cols starting at 16*seg of row y, chan c
    {
        const int c   = tid >> 5;          // 32 jobs per channel
        const int y   = (tid >> 2) & 7;
        const int seg = tid & 3;
        const int base = (c * SROWS + y) * SSTR2 + (seg << 3);

        float r0[20], r1[20], r2[20];  // vertical sums over 20 halo cols
        #pragma unroll
        for (int k = 0; k < 10; ++k) {
            __half2 p0 = s_in[base              + k];
            __half2 p1 = s_in[base +   SSTR2    + k];
            __half2 p2 = s_in[base + 2*SSTR2    + k];
            __half2 p3 = s_in[base + 3*SSTR2    + k];
            __half2 p4 = s_in[base + 4*SSTR2    + k];
            __half2 v1 = __hadd2(p1, p3);
            __half2 v2 = __hadd2(p0, p4);
            float2 f0 = __half22float2(p2);
            float2 f1 = __half22float2(v1);
            float2 f2 = __half22float2(v2);
            r0[2*k] = f0.x; r0[2*k+1] = f0.y;
            r1[2*k] = f1.x; r1[2*k+1] = f1.y;
            r2[2*k] = f2.x; r2[2*k+1] = f2.y;
        }
        float A  = s_coef[c*8+0], Bc = s_coef[c*8+1], Cc = s_coef[c*8+2];
        float Dc = s_coef[c*8+3], Ec = s_coef[c*8+4], Fc = s_coef[c*8+5];
        float bias = s_coef[c*8+6];

        const int zbase = (c * SLAB + y) * ZSTR2 + (seg << 3);
        #pragma unroll
        for (int j2 = 0; j2 < 8; ++j2) {
            const int j = 2 * j2;
            // packed: lane .x = pixel j, lane .y = pixel j+1 -> v_pk_fma_f32
            v2f v = A  * PV(r0, j+2)
                  + Bc * (PV(r0, j+1) + PV(r0, j+3) + PV(r1, j+2))
                  + Cc * (PV(r1, j+1) + PV(r1, j+3))
                  + Dc * (PV(r0, j)   + PV(r0, j+4) + PV(r2, j+2))
                  + Ec * (PV(r1, j)   + PV(r1, j+4) + PV(r2, j+1) + PV(r2, j+3))
                  + Fc * (PV(r2, j)   + PV(r2, j+4))
                  + bias;
            v2f w = 0.01f * v;
            s_z[zbase + j2] = __floats2half2_rn(fmaxf(v.x, w.x), fmaxf(v.y, w.y));
        }
    }
    __syncthreads();

    // ---- phase 2: per-pixel 8x8 GEMMs + residual + tanh ----
    float* outb = out + (size_t)b * (HIDDEN * RES * RES);
    {
        const int q  = tid;          // pixel-pair index, pixels (2q, 2q+1)
        const int y  = q >> 5;
        const int xh = q & 31;       // x0 = 2*xh

        v2f z2[8];
        #pragma unroll
        for (int c = 0; c < 8; ++c) {
            float2 f = __half22float2(s_z[(c * SLAB + y) * ZSTR2 + xh]);
            z2[c] = (v2f){f.x, f.y};
        }
        v2f h2[8];
        #pragma unroll
        for (int o = 0; o < 8; ++o) {
            float bb = b2[o];                   // uniform -> s_load
            v2f a = (v2f){bb, bb};
            #pragma unroll
            for (int i = 0; i < 8; ++i)
                a += w2[o*8+i] * z2[i];         // v_pk_fma_f32, SGPR splat
            v2f t = 0.01f * a;
            h2[o] = (v2f){fmaxf(a.x, t.x), fmaxf(a.y, t.y)};
        }
        #pragma unroll
        for (int o = 0; o < 8; ++o) {
            float bb = b3[o];
            v2f g = (v2f){bb, bb};
            #pragma unroll
            for (int i = 0; i < 8; ++i)
                g += w3[o*8+i] * h2[i];
            float2 ps = __half22float2(s_in[(o * SROWS + y + 2) * SSTR2 + xh + 1]);
            float t0 = ps.x + g.x;
            float t1 = ps.y + g.y;
            // tanh(x) = 1 - 2/(exp(2x)+1); exp->inf / ->0 saturate correctly
            float e0 = __expf(2.f * t0);
            float e1 = __expf(2.f * t1);
            float o0 = 1.f - 2.f * __builtin_amdgcn_rcpf(e0 + 1.f);
            float o1 = 1.f - 2.f * __builtin_amdgcn_rcpf(e1 + 1.f);
            *(float2*)(outb + (o << 12) + ((y0 + y) << 6) + 2*xh) = make_float2(o0, o1);
        }
    }
}

extern "C" void kernel_launch(void* const* d_in, const int* in_sizes, int n_in,
                              void* d_out, int out_size, void* d_ws, size_t ws_size,
                              hipStream_t stream) {
    const float* psi     = (const float*)d_in[0];
    const float* filter1 = (const float*)d_in[1];
    const float* bias1   = (const float*)d_in[2];
    const float* w2      = (const float*)d_in[3];
    const float* b2      = (const float*)d_in[4];
    const float* w3      = (const float*)d_in[5];
    const float* b3      = (const float*)d_in[6];
    float* out = (float*)d_out;

    dim3 grid(2048 * 8);
    dim3 block(256);
    hipLaunchKernelGGL(ca_fused, grid, block, 0, stream,
                       psi, filter1, bias1, w2, b2, w3, b3, out);
}

// Round 2
// 479.250 us; speedup vs baseline: 1.1400x; 1.0223x over previous
//
#include <hip/hip_runtime.h>
#include <hip/hip_fp16.h>

// Fused neural-CA step on MI355X (gfx950).
//   z  = leaky(depthwise_conv5x5_D4sym(psi) + b1)
//   h  = leaky(w2 z + b2);  out = tanh(psi + w3 h + b3)
//
// Round 3 changes (vs 187.5us/dispatch round 2):
//  - Staging loop: zero div/mod (c is a compile-time unroll index,
//    r=tid>>4, q=tid&15), float4 (16B) global loads, paired LDS writes.
//    Was ~200 VALU instr/thread of pure addressing; now ~60.
//  - SSTR2 35 -> 36: every conv-window base is 16B-aligned, so phase-1
//    LDS reads become 2x ds_read_b128 + 1x ds_read_b64 per row
//    (15 LDS ops/thread instead of 50). Lane start-banks spread over
//    8 positions x 4-dword spans -> conflict-free in aggregate.
//  - Explicit zero writes for pad pairs 0 and 33 (old loop did it inline).
//  - __launch_bounds__(256,7): LDS caps at 7 blocks/CU (22.5KB), so give
//    the register allocator ~72 VGPRs instead of 64.
//  - Phase-2, packed-f32 math, fp16 LDS formats, D4 decomposition, fast
//    tanh unchanged.

#define HIDDEN 8
#define RES    64
#define SLAB   8
#define SROWS  12   // SLAB + 4 halo rows
#define SSTR2  36   // psi tile row stride in __half2 units; rows 16B-aligned
#define ZSTR2  33   // z tile row stride in __half2 units

typedef float v2f __attribute__((ext_vector_type(2)));
typedef unsigned int u32;
typedef u32 u32x4 __attribute__((ext_vector_type(4)));
typedef u32 u32x2 __attribute__((ext_vector_type(2)));

#define PV(a, i) ((v2f){ (a)[(i)], (a)[(i) + 1] })

static __device__ __forceinline__ __half2 bch2(u32 u) {
    return __builtin_bit_cast(__half2, u);
}

// read 10 consecutive __half2 pairs from a 16B-aligned LDS row:
// ds_read_b128 + ds_read_b128 + ds_read_b64
static __device__ __forceinline__ void load_row10(const u32* rp, __half2 d[10]) {
    u32x4 a = *(const u32x4*)rp;
    u32x4 b = *(const u32x4*)(rp + 4);
    u32x2 c = *(const u32x2*)(rp + 8);
    d[0] = bch2(a.x); d[1] = bch2(a.y); d[2] = bch2(a.z); d[3] = bch2(a.w);
    d[4] = bch2(b.x); d[5] = bch2(b.y); d[6] = bch2(b.z); d[7] = bch2(b.w);
    d[8] = bch2(c.x); d[9] = bch2(c.y);
}

__global__ __launch_bounds__(256, 7)
void ca_fused(const float* __restrict__ psi,
              const float* __restrict__ filter1,
              const float* __restrict__ bias1,
              const float* __restrict__ w2,
              const float* __restrict__ b2,
              const float* __restrict__ w3,
              const float* __restrict__ b3,
              float* __restrict__ out)
{
    // layout per row (pairs): 0 = zero pad, 1..32 = data (gx 0..63),
    // 33 = zero pad, 34..35 unused. Row byte stride 144 (16B-aligned).
    __shared__ __align__(16) __half2 s_in[HIDDEN * SROWS * SSTR2]; // 13824 B
    __shared__ __align__(16) __half2 s_z [HIDDEN * SLAB  * ZSTR2]; //  8448 B
    __shared__ float s_coef[HIDDEN * 8];   // A,B,C,D,E,F,bias1,pad

    const int tid  = threadIdx.x;
    const int b    = blockIdx.x >> 3;
    const int slab = blockIdx.x & 7;
    const int y0   = slab * SLAB;

    const float* psib = psi + (size_t)b * (HIDDEN * RES * RES);

    // ---- totalistic coefficients, one thread per channel ----
    if (tid < HIDDEN) {
        const float* f = filter1 + tid * 25;
        float x[25];
        float m = 0.f;
        #pragma unroll
        for (int i = 0; i < 25; ++i) { x[i] = f[i]; m += x[i]; }
        m *= 0.04f;  // /25
        float A = x[12] - m;                                          // center
        float B = 0.25f  * (x[7]+x[17]+x[11]+x[13]) - m;              // edge-1
        float C = 0.25f  * (x[6]+x[8]+x[16]+x[18]) - m;               // diag-1
        float D = 0.25f  * (x[2]+x[22]+x[10]+x[14]) - m;              // edge-2
        float E = 0.125f * (x[1]+x[3]+x[21]+x[23]+x[5]+x[15]+x[9]+x[19]) - m; // knight
        float F = 0.25f  * (x[0]+x[4]+x[20]+x[24]) - m;               // corner
        s_coef[tid*8+0] = A; s_coef[tid*8+1] = B; s_coef[tid*8+2] = C;
        s_coef[tid*8+3] = D; s_coef[tid*8+4] = E; s_coef[tid*8+5] = F;
        s_coef[tid*8+6] = bias1[tid];
    }

    // ---- zero the pad pairs (0 and 33) of every row ----
    {
        const int c    = tid >> 5;
        const int r    = (tid >> 1) & 15;
        const int side = tid & 1;
        if (r < SROWS)
            s_in[(c * SROWS + r) * SSTR2 + (side ? 33 : 0)] =
                __floats2half2_rn(0.f, 0.f);
    }

    // ---- stage psi slab into LDS as fp16 pairs ----
    // job = (c=i, r=tid>>4, quad=tid&15): one float4 = gx 4q..4q+3
    {
        const int r = tid >> 4;      // 0..15, active if < SROWS
        const int q = tid & 15;
        const int gy = y0 - 2 + r;
        const bool rowok = (r < SROWS);
        const bool valid = rowok && ((unsigned)gy < RES);
        #pragma unroll
        for (int i = 0; i < HIDDEN; ++i) {   // i == channel, compile-time
            if (rowok) {
                float4 v = make_float4(0.f, 0.f, 0.f, 0.f);
                if (valid)
                    v = *(const float4*)(psib + (i << 12) + (gy << 6) + (q << 2));
                const int pb = (i * SROWS + r) * SSTR2 + 1 + 2 * q;
                s_in[pb]     = __floats2half2_rn(v.x, v.y);
                s_in[pb + 1] = __floats2half2_rn(v.z, v.w);
            }
        }
    }
    __syncthreads();

    // ---- phase 1: depthwise conv + bias + leaky -> s_z ----
    // job = (c, y, seg): 16 output cols starting at 16*seg of row y, chan c
    {
        const int c   = tid >> 5;
        const int y   = (tid >> 2) & 7;
        const int seg = tid & 3;
        const u32* rp = (const u32*)s_in + (c * SROWS + y) * SSTR2 + (seg << 3);

        // vertical sums in fp16: h0 = center row, h1 = rows +-1, h2 = rows +-2
        __half2 h0[10], h1[10], h2[10], tmp[10];
        load_row10(rp + 0 * SSTR2, h2);
        load_row10(rp + 4 * SSTR2, tmp);
        #pragma unroll
        for (int k = 0; k < 10; ++k) h2[k] = __hadd2(h2[k], tmp[k]);
        load_row10(rp + 1 * SSTR2, h1);
        load_row10(rp + 3 * SSTR2, tmp);
        #pragma unroll
        for (int k = 0; k < 10; ++k) h1[k] = __hadd2(h1[k], tmp[k]);
        load_row10(rp + 2 * SSTR2, h0);

        float r0[20], r1[20], r2[20];
        #pragma unroll
        for (int k = 0; k < 10; ++k) {
            float2 f0 = __half22float2(h0[k]);
            float2 f1 = __half22float2(h1[k]);
            float2 f2 = __half22float2(h2[k]);
            r0[2*k] = f0.x; r0[2*k+1] = f0.y;
            r1[2*k] = f1.x; r1[2*k+1] = f1.y;
            r2[2*k] = f2.x; r2[2*k+1] = f2.y;
        }
        float A  = s_coef[c*8+0], Bc = s_coef[c*8+1], Cc = s_coef[c*8+2];
        float Dc = s_coef[c*8+3], Ec = s_coef[c*8+4], Fc = s_coef[c*8+5];
        float bias = s_coef[c*8+6];

        const int zbase = (c * SLAB + y) * ZSTR2 + (seg << 3);
        #pragma unroll
        for (int j2 = 0; j2 < 8; ++j2) {
            const int j = 2 * j2;
            // packed: lane .x = pixel j, lane .y = pixel j+1 -> v_pk_fma_f32
            v2f v = A  * PV(r0, j+2)
                  + Bc * (PV(r0, j+1) + PV(r0, j+3) + PV(r1, j+2))
                  + Cc * (PV(r1, j+1) + PV(r1, j+3))
                  + Dc * (PV(r0, j)   + PV(r0, j+4) + PV(r2, j+2))
                  + Ec * (PV(r1, j)   + PV(r1, j+4) + PV(r2, j+1) + PV(r2, j+3))
                  + Fc * (PV(r2, j)   + PV(r2, j+4))
                  + bias;
            v2f w = 0.01f * v;
            s_z[zbase + j2] = __floats2half2_rn(fmaxf(v.x, w.x), fmaxf(v.y, w.y));
        }
    }
    __syncthreads();

    // ---- phase 2: per-pixel 8x8 GEMMs + residual + tanh ----
    float* outb = out + (size_t)b * (HIDDEN * RES * RES);
    {
        const int q  = tid;          // pixel-pair index, pixels (2q, 2q+1)
        const int y  = q >> 5;
        const int xh = q & 31;       // x0 = 2*xh

        v2f z2[8];
        #pragma unroll
        for (int c = 0; c < 8; ++c) {
            float2 f = __half22float2(s_z[(c * SLAB + y) * ZSTR2 + xh]);
            z2[c] = (v2f){f.x, f.y};
        }
        v2f h2[8];
        #pragma unroll
        for (int o = 0; o < 8; ++o) {
            float bb = b2[o];                   // uniform -> s_load
            v2f a = (v2f){bb, bb};
            #pragma unroll
            for (int i = 0; i < 8; ++i)
                a += w2[o*8+i] * z2[i];         // v_pk_fma_f32, SGPR splat
            v2f t = 0.01f * a;
            h2[o] = (v2f){fmaxf(a.x, t.x), fmaxf(a.y, t.y)};
        }
        #pragma unroll
        for (int o = 0; o < 8; ++o) {
            float bb = b3[o];
            v2f g = (v2f){bb, bb};
            #pragma unroll
            for (int i = 0; i < 8; ++i)
                g += w3[o*8+i] * h2[i];
            float2 ps = __half22float2(s_in[(o * SROWS + y + 2) * SSTR2 + xh + 1]);
            float t0 = ps.x + g.x;
            float t1 = ps.y + g.y;
            // tanh(x) = 1 - 2/(exp(2x)+1); exp->inf / ->0 saturate correctly
            float e0 = __expf(2.f * t0);
            float e1 = __expf(2.f * t1);
            float o0 = 1.f - 2.f * __builtin_amdgcn_rcpf(e0 + 1.f);
            float o1 = 1.f - 2.f * __builtin_amdgcn_rcpf(e1 + 1.f);
            *(float2*)(outb + (o << 12) + ((y0 + y) << 6) + 2*xh) = make_float2(o0, o1);
        }
    }
}

extern "C" void kernel_launch(void* const* d_in, const int* in_sizes, int n_in,
                              void* d_out, int out_size, void* d_ws, size_t ws_size,
                              hipStream_t stream) {
    const float* psi     = (const float*)d_in[0];
    const float* filter1 = (const float*)d_in[1];
    const float* bias1   = (const float*)d_in[2];
    const float* w2      = (const float*)d_in[3];
    const float* b2      = (const float*)d_in[4];
    const float* w3      = (const float*)d_in[5];
    const float* b3      = (const float*)d_in[6];
    float* out = (float*)d_out;

    dim3 grid(2048 * 8);
    dim3 block(256);
    hipLaunchKernelGGL(ca_fused, grid, block, 0, stream,
                       psi, filter1, bias1, w2, b2, w3, b3, out);
}